// Round 10
// baseline (6580.157 us; speedup 1.0000x reference)
//
#include <hip/hip_runtime.h>
#include <hip/hip_fp16.h>

// LSTM B=8192 S=1024 H=256 — round 17: r16's weave + CORRECT cross-wave DMA.
// r16 failed correctness: DMA'd peer half consumed in the SAME region with
// only a per-wave vmcnt(0) — other waves' slices not yet visible (stale rows,
// absmax 2.8e-3). Fix (r13's lead-wave trick): EVERY wave DMAs the ENTIRE
// 8KB peer half (8x global_load_lds, identical-write race benign), so its own
// vmcnt(0) covers all rows it reads. No extra barrier; schedule unchanged:
//   region (s,t): [acc-init(s); EW(s^1,prev); K-own(s)]   <- independent ->
//                  compiler can weave EW's trans-VALU into K's MFMA shadows
//                 poll pfl[s]>=t (~1500cy margin, set >=1 region ago = fresh)
//                 dup-DMA peer half; vmcnt(0); K-peer(s); barrier; flag.
// - own k-half: EW ds_writes stg[set][0] one region before K reads it
// - publish stores issue ~2000cy before the barrier -> drain ~free
// - t=0 peeled (LDS zero = h_0); loop body branch-free except the poll
// - pair blocks stay lockstep (same region sequence) -> x L2 locality holds
//   (r13/r14's FETCH blowup came from pair drift, not dup DMA)
// EW: 7 trans/elem, weights pre-scaled by log2e (x2 c gate). 256 blocks x
// 512 thr, 1 block/CU; pairs {B,B^8} share 64 rows = 2 staggered sets of 32.

typedef _Float16 f16x8 __attribute__((ext_vector_type(8)));
typedef float f32x4 __attribute__((ext_vector_type(4)));
typedef unsigned int u32;
typedef unsigned short u16;

#define WINT_OFF 0u
#define W0B_OFF  524288u
#define FLAG_OFF 528384u   // int[256 blocks][2 sets][16] = 32 KB
#define PUB_OFF  1048576u  // u16[(set*2+par)*128+pair][2 half][4096] = 8 MB

static __device__ __forceinline__ float fast_exp2(float x) {
#if __has_builtin(__builtin_amdgcn_exp2f)
  return __builtin_amdgcn_exp2f(x);
#else
  return exp2f(x);
#endif
}
static __device__ __forceinline__ float fast_rcp(float x) {
#if __has_builtin(__builtin_amdgcn_rcpf)
  return __builtin_amdgcn_rcpf(x);
#else
  return 1.0f / x;
#endif
}
static __device__ __forceinline__ u16 f16b(float f) {
  union { _Float16 h; u16 u; } cv; cv.h = (_Float16)f; return cv.u;
}
static __device__ __forceinline__ float h2f(u16 u) {
  union { u16 u; _Float16 h; } cv; cv.u = u; return (float)cv.h;
}
static __device__ __forceinline__ u16* pub_base(u16* pub, int set, int par,
                                                int pid, int half) {
  return pub + ((size_t)(((set * 2 + par) * 128 + pid) * 2 + half) << 12);
}

// Wint[n][k], n = g*256 + j, PRE-SCALED by log2e (x2 for the c gate);
// w0b[n] = packed fp16 {w0*scale, bias*scale}.
__global__ void lstm_prep(const float* __restrict__ Wf, const float* __restrict__ Wi,
                          const float* __restrict__ Wc, const float* __restrict__ Wo,
                          const float* __restrict__ bf_, const float* __restrict__ bi_,
                          const float* __restrict__ bc_, const float* __restrict__ bo_,
                          u16* __restrict__ Wint, u32* __restrict__ w0b) {
  int n = blockIdx.x;       // 0..1023
  int k = threadIdx.x;      // 0..255
  int g = n >> 8, j = n & 255;
  const float* Ws = (g == 0) ? Wf : (g == 1) ? Wi : (g == 2) ? Wc : Wo;
  const float scale = (g == 2) ? 2.88539008f : 1.44269504f;  // 2*log2e : log2e
  Wint[n * 256 + k] = f16b(Ws[j * 257 + 1 + k] * scale);
  if (k == 0) {
    const float* bs = (g == 0) ? bf_ : (g == 1) ? bi_ : (g == 2) ? bc_ : bo_;
    w0b[n] = (u32)f16b(Ws[j * 257] * scale) | ((u32)f16b(bs[j] * scale) << 16);
  }
}

// Zero flags; out = bout. (pub needs no zeroing: h_0 lives only in zeroed LDS,
// every pub read is flag-gated behind a same-launch write.)
__global__ void lstm_zero(uint4* __restrict__ flags4, float* __restrict__ out,
                          const float* __restrict__ bout) {
  int idx = blockIdx.x * 256 + threadIdx.x;
  if (idx < 2048) flags4[idx] = uint4{0, 0, 0, 0};      // 32 KB flags
  else if (idx < 10240) out[idx - 2048] = bout[0];      // 8192 outputs
}

__global__ __launch_bounds__(512, 2) void lstm_main(
    const u16* __restrict__ Wint, const u32* __restrict__ w0b,
    const float* __restrict__ x, const float* __restrict__ Wout,
    float* __restrict__ out, u16* __restrict__ pub, int* __restrict__ flags) {

  // [set][0=own k-half,1=peer][32 rows x 128 cols] = 32 KB, single-buffered
  // (own: ds_written region n, read n+1; peer: dup-DMA'd and read in the same
  //  region, per-wave complete via vmcnt(0); WAR on peer slot = 2 barriers)
  __shared__ __align__(16) u16 stg[2][2][4096];

  const int tid  = threadIdx.x;
  const int wv   = tid >> 6;
  const int lane = tid & 63;
  const int l15  = lane & 15;
  const int quad = lane >> 4;
  const int B    = blockIdx.x;
  const int mi   = (B >> 3) & 1;
  const int peer = B ^ 8;
  const int pid  = (B & 7) | ((B >> 4) << 3);   // pair 0..127
  const int rows0 = pid * 64;

  // ---- one-time: W A-fragments (128 regs, STATIC indices) ----
  f16x8 wfrag[4][8];
#pragma unroll
  for (int g = 0; g < 4; ++g)
#pragma unroll
    for (int hm = 0; hm < 2; ++hm)
#pragma unroll
      for (int ktl = 0; ktl < 4; ++ktl) {
        int kbase = (hm == 0 ? mi : 1 - mi) * 128 + ktl * 32;  // runtime, addr only
        wfrag[g][hm * 4 + ktl] = *(const f16x8*)(Wint +
            (size_t)(g * 256 + mi * 128 + wv * 16 + l15) * 256 + kbase + quad * 8);
      }
  // packed w0/bias (16 regs; unpacked per-region — fits with doubled acc)
  uint4 w0bv[4];
#pragma unroll
  for (int g = 0; g < 4; ++g)
    w0bv[g] = *(const uint4*)(w0b + g * 256 + mi * 128 + wv * 16 + quad * 4);

  // zero stg (h_0 images = 0): 32 KB = 2048 uint4
#pragma unroll
  for (int i = 0; i < 4; ++i) ((uint4*)stg)[tid + i * 512] = uint4{0, 0, 0, 0};

  float cst[2][2][4];   // [set][bt][r]: cell (b = bt*16+l15, j = wv*16+quad*4+r)
#pragma unroll
  for (int s = 0; s < 2; ++s)
#pragma unroll
    for (int bt = 0; bt < 2; ++bt)
#pragma unroll
      for (int r = 0; r < 4; ++r) cst[s][bt][r] = 0.0f;

  // both sets' accumulators live across regions (EW deferred one region)
  f32x4 acc[2][4][2];

  const float* xq = x + (size_t)rows0 * 1024;
  float xcur[2][2];
#pragma unroll
  for (int s = 0; s < 2; ++s)
#pragma unroll
    for (int bt = 0; bt < 2; ++bt)
      xcur[s][bt] = xq[(size_t)(s * 32 + bt * 16 + l15) * 1024];

  int* const myflag = flags + B * 32;
  int* const pfl    = flags + peer * 32;

  __syncthreads();

// acc init for set S at step t (packed w0/bias unpack) + x prefetch for t+1
#define ACC_INIT(S) do {                                                       \
    _Pragma("unroll")                                                          \
    for (int g_ = 0; g_ < 4; ++g_) {                                           \
      u32 pka_[4] = {w0bv[g_].x, w0bv[g_].y, w0bv[g_].z, w0bv[g_].w};          \
      _Pragma("unroll")                                                        \
      for (int r_ = 0; r_ < 4; ++r_) {                                         \
        float w0_ = h2f((u16)pka_[r_]), bs_ = h2f((u16)(pka_[r_] >> 16));      \
        acc[S][g_][0][r_] = xcur[S][0] * w0_ + bs_;                            \
        acc[S][g_][1][r_] = xcur[S][1] * w0_ + bs_;                            \
      }                                                                        \
    }                                                                          \
    _Pragma("unroll")                                                          \
    for (int bt_ = 0; bt_ < 2; ++bt_)                                          \
      xcur[S][bt_] = xq[(size_t)((S) * 32 + bt_ * 16 + l15) * 1024 +           \
                        ((t + 1) & 1023)];                                     \
  } while (0)

// EW for set ES: drain acc[ES] (filled by K(ES) LAST region), update cst[ES],
// publish h_{TP1}(ES): ds_write own half to stg[ES][0] + global pub par TP1&1.
#define EW_PUB(ES, TP1) do {                                                   \
    u16* pb_ = pub_base(pub, ES, (TP1) & 1, pid, mi);                          \
    _Pragma("unroll")                                                          \
    for (int bt_ = 0; bt_ < 2; ++bt_) {                                        \
      int b_ = bt_ * 16 + l15;                                                 \
      u32 lo_, hi_;                                                            \
      {                                                                        \
        float h0_, h1_, h2_, h3_;                                              \
        _Pragma("unroll")                                                      \
        for (int r_ = 0; r_ < 4; ++r_) {                                       \
          float fg_ = acc[ES][0][bt_][r_], ig_ = acc[ES][1][bt_][r_];          \
          float cg_ = acc[ES][2][bt_][r_], og_ = acc[ES][3][bt_][r_];          \
          float Ef_ = fast_exp2(-fg_);                                         \
          float Ei_ = fast_exp2(-ig_);                                         \
          float C_  = fast_exp2(cg_);                                          \
          float X_  = 1.0f + Ef_;                                              \
          float Y_  = (1.0f + Ei_) * (C_ + 1.0f);                              \
          float num_ = cst[ES][bt_][r_] * Y_ + (C_ - 1.0f) * X_;               \
          float c2_  = num_ * fast_rcp(X_ * Y_);                               \
          cst[ES][bt_][r_] = c2_;                                              \
          float cc_ = fminf(fmaxf(c2_, -40.0f), 40.0f);                        \
          float T_  = fast_exp2(2.88539008f * cc_);                            \
          float Eo_ = fast_exp2(-og_);                                         \
          float hv_ = (T_ - 1.0f) * fast_rcp((1.0f + Eo_) * (T_ + 1.0f));      \
          if (r_ == 0) h0_ = hv_; else if (r_ == 1) h1_ = hv_;                 \
          else if (r_ == 2) h2_ = hv_; else h3_ = hv_;                         \
        }                                                                      \
        lo_ = (u32)f16b(h0_) | ((u32)f16b(h1_) << 16);                         \
        hi_ = (u32)f16b(h2_) | ((u32)f16b(h3_) << 16);                         \
      }                                                                        \
      int c16_ = wv * 2 + (quad >> 1);                                         \
      int off_ = b_ * 128 + (c16_ ^ (b_ & 15)) * 8 + (quad & 1) * 4;           \
      *(uint2*)(&stg[ES][0][0] + off_) = uint2{lo_, hi_};                      \
      *(uint2*)(pb_ + off_) = uint2{lo_, hi_};                                 \
    }                                                                          \
  } while (0)

// K half HM of set S: 4 slots x (2 ds_read_b128 + 8 MFMA) into acc[S].
#define KHALF(S, HM) do {                                                      \
    _Pragma("unroll")                                                          \
    for (int ktl_ = 0; ktl_ < 4; ++ktl_) {                                     \
      f16x8 bb_[2];                                                            \
      _Pragma("unroll")                                                        \
      for (int bt_ = 0; bt_ < 2; ++bt_) {                                      \
        int b_ = bt_ * 16 + l15;                                               \
        int cp_ = (ktl_ * 4 + quad) ^ (b_ & 15);                               \
        bb_[bt_] = *(const f16x8*)(&stg[S][HM][0] + b_ * 128 + cp_ * 8);       \
      }                                                                        \
      _Pragma("unroll")                                                        \
      for (int g_ = 0; g_ < 4; ++g_)                                           \
        _Pragma("unroll")                                                      \
        for (int bt_ = 0; bt_ < 2; ++bt_)                                      \
          acc[S][g_][bt_] = __builtin_amdgcn_mfma_f32_16x16x32_f16(            \
              wfrag[g_][(HM) * 4 + ktl_], bb_[bt_], acc[S][g_][bt_], 0, 0, 0); \
    }                                                                          \
  } while (0)

// Duplicated DMA: THIS wave loads the ENTIRE 8KB peer half of set S, step T
// (8 x 1KB segments; all waves write identical data — benign). The wave's own
// vmcnt(0) then covers every row it reads in KHALF(S,1).
#define DMA_PEER_FULL(S, T) do {                                               \
    const u16* srcP_ = pub_base(pub, S, (T) & 1, pid, 1 - mi);                 \
    _Pragma("unroll")                                                          \
    for (int i_ = 0; i_ < 8; ++i_)                                             \
      __builtin_amdgcn_global_load_lds(                                        \
          (const __attribute__((address_space(1))) u32*)(srcP_ + i_ * 512 +    \
                                                         lane * 8),            \
          (__attribute__((address_space(3))) u32*)(&stg[S][1][i_ * 512]),      \
          16, 0, 0);                                                           \
  } while (0)

  // ---- peeled t=0 (h_0 = zeroed LDS; no EW/poll/DMA yet) ----
  {
    const int t = 0;
    ACC_INIT(0);
    KHALF(0, 0); KHALF(0, 1);
    __syncthreads();
    ACC_INIT(1);
    EW_PUB(0, 1);                       // h_1(0) from K(0,0)'s acc
    KHALF(1, 0); KHALF(1, 1);
    __syncthreads();
    if (tid == 0)
      __hip_atomic_store(myflag + 0, 1, __ATOMIC_RELAXED,
                         __HIP_MEMORY_SCOPE_AGENT);
  }

#pragma unroll 1
  for (int t = 1; t < 1024; ++t) {
    // ---- region (0,t): acc0 | EW(1,t-1)->h_t(1) | K-own(0) | poll+dupDMA | K-peer(0)
    ACC_INIT(0);
    EW_PUB(1, t);
    KHALF(0, 0);
    while (__hip_atomic_load(pfl + 0, __ATOMIC_RELAXED,
                             __HIP_MEMORY_SCOPE_AGENT) < t)
      __builtin_amdgcn_s_sleep(1);
    DMA_PEER_FULL(0, t);
    asm volatile("s_waitcnt vmcnt(0)" ::: "memory");
    KHALF(0, 1);
    __syncthreads();
    if (tid == 0)
      __hip_atomic_store(myflag + 16, t, __ATOMIC_RELAXED,
                         __HIP_MEMORY_SCOPE_AGENT);

    // ---- region (1,t): acc1 | EW(0,t)->h_{t+1}(0) | K-own(1) | poll+dupDMA | K-peer(1)
    ACC_INIT(1);
    EW_PUB(0, t + 1);
    KHALF(1, 0);
    while (__hip_atomic_load(pfl + 16, __ATOMIC_RELAXED,
                             __HIP_MEMORY_SCOPE_AGENT) < t)
      __builtin_amdgcn_s_sleep(1);
    DMA_PEER_FULL(1, t);
    asm volatile("s_waitcnt vmcnt(0)" ::: "memory");
    KHALF(1, 1);
    __syncthreads();
    if (tid == 0)
      __hip_atomic_store(myflag + 0, t + 1, __ATOMIC_RELAXED,
                         __HIP_MEMORY_SCOPE_AGENT);
  }

  // ---- epilogue: EW(1,1023) -> h_1024(1), parity 0 publish ----
  EW_PUB(1, 1024);
  __syncthreads();   // implicit vmcnt(0): epilogue publish visible

  // ---- out[b] += (own j-half of h_1024) . Wout  (out pre-set to bout) ----
  if (tid < 64) {
    int s = tid >> 5, b = tid & 31;
    const u16* pbase = pub_base(pub, s, 0, pid, mi);  // parity of t=1024 is 0
    float a = 0.0f;
#pragma unroll
    for (int c = 0; c < 16; ++c) {
      f16x8 hv = *(const f16x8*)(pbase + b * 128 + ((c ^ (b & 15)) * 8));
#pragma unroll
      for (int e = 0; e < 8; ++e) a += (float)hv[e] * Wout[mi * 128 + c * 8 + e];
    }
    atomicAdd(&out[rows0 + s * 32 + b], a);
  }
#undef ACC_INIT
#undef EW_PUB
#undef KHALF
#undef DMA_PEER_FULL
}

extern "C" void kernel_launch(void* const* d_in, const int* in_sizes, int n_in,
                              void* d_out, int out_size, void* d_ws, size_t ws_size,
                              hipStream_t stream) {
  const float* x    = (const float*)d_in[0];
  const float* Wf   = (const float*)d_in[1];
  const float* bf_  = (const float*)d_in[2];
  const float* Wi   = (const float*)d_in[3];
  const float* bi_  = (const float*)d_in[4];
  const float* Wc   = (const float*)d_in[5];
  const float* bc_  = (const float*)d_in[6];
  const float* Wo   = (const float*)d_in[7];
  const float* bo_  = (const float*)d_in[8];
  const float* Wout = (const float*)d_in[9];
  const float* bout = (const float*)d_in[10];

  u16* Wint  = (u16*)((char*)d_ws + WINT_OFF);
  u32* w0b   = (u32*)((char*)d_ws + W0B_OFF);
  int* flags = (int*)((char*)d_ws + FLAG_OFF);
  u16* pub   = (u16*)((char*)d_ws + PUB_OFF);

  lstm_prep<<<1024, 256, 0, stream>>>(Wf, Wi, Wc, Wo, bf_, bi_, bc_, bo_, Wint, w0b);
  lstm_zero<<<40, 256, 0, stream>>>((uint4*)flags, (float*)d_out, bout);
  lstm_main<<<256, 512, 0, stream>>>(Wint, w0b, x, Wout, (float*)d_out, pub, flags);
}

// Round 11
// 4956.621 us; speedup vs baseline: 1.3275x; 1.3275x over previous
//
#include <hip/hip_runtime.h>
#include <hip/hip_fp16.h>

// LSTM B=8192 S=1024 H=256 — round 18: gate-staggered K (in-wave EW/MFMA
// overlap), transport = r15 VERBATIM.
// r17 post-mortem: dup-DMA thrashed L2 (pub 8MB > 4MB/XCD L2): WRITE 8x.
// Slack argument: any EW-deferral delays the producer flag by exactly the
// consumer slack it would gain -> r15's transport (point-of-need poll, slice
// DMA, next-substep consume, single barrier) is the only working pattern.
// r15 profile: VALU 1330 + MFMA 1020 + sync 360 cy/substep/SIMD, SERIAL
// because EW depends on the whole K. This round splits K gate-major:
//   bt0: bb[8] loads; gateF chain(8 MFMA); gateI chain || exp2(-f) in-place;
//        gateC || exp2(-i); gateO || exp2(c); combine0+publish0 (weaves with
//        bt1's chains);
//   bt1: same; then poll+DMA (r15); combine1+publish1 covers DMA; barrier.
// Front-end trans overwrite acc (no extra regs); bb[8]=32 VGPR funded by
// repacking w0/bias (16 regs). ~400cy/substep of VALU moves under the MFMA
// pipe's slack. 1 dependent MFMA chain/wave x 2 waves/SIMD keeps pipe full
// (II<=16cy). 256 blocks x 512 thr; pairs {B,B^8} share 64 rows = 2 sets.

typedef _Float16 f16x8 __attribute__((ext_vector_type(8)));
typedef float f32x4 __attribute__((ext_vector_type(4)));
typedef unsigned int u32;
typedef unsigned short u16;

#define WINT_OFF 0u
#define W0B_OFF  524288u
#define FLAG_OFF 528384u   // int[256 blocks][2 sets][16] = 32 KB
#define PUB_OFF  1048576u  // u16[(set*2+par)*128+pair][2 half][4096] = 8 MB

static __device__ __forceinline__ float fast_exp2(float x) {
#if __has_builtin(__builtin_amdgcn_exp2f)
  return __builtin_amdgcn_exp2f(x);
#else
  return exp2f(x);
#endif
}
static __device__ __forceinline__ float fast_rcp(float x) {
#if __has_builtin(__builtin_amdgcn_rcpf)
  return __builtin_amdgcn_rcpf(x);
#else
  return 1.0f / x;
#endif
}
static __device__ __forceinline__ u16 f16b(float f) {
  union { _Float16 h; u16 u; } cv; cv.h = (_Float16)f; return cv.u;
}
static __device__ __forceinline__ float h2f(u16 u) {
  union { u16 u; _Float16 h; } cv; cv.u = u; return (float)cv.h;
}
static __device__ __forceinline__ u16* pub_base(u16* pub, int set, int par,
                                                int pid, int half) {
  return pub + ((size_t)(((set * 2 + par) * 128 + pid) * 2 + half) << 12);
}

// Wint[n][k], n = g*256 + j, PRE-SCALED by log2e (x2 for the c gate);
// w0b[n] = packed fp16 {w0*scale, bias*scale}.
__global__ void lstm_prep(const float* __restrict__ Wf, const float* __restrict__ Wi,
                          const float* __restrict__ Wc, const float* __restrict__ Wo,
                          const float* __restrict__ bf_, const float* __restrict__ bi_,
                          const float* __restrict__ bc_, const float* __restrict__ bo_,
                          u16* __restrict__ Wint, u32* __restrict__ w0b) {
  int n = blockIdx.x;       // 0..1023
  int k = threadIdx.x;      // 0..255
  int g = n >> 8, j = n & 255;
  const float* Ws = (g == 0) ? Wf : (g == 1) ? Wi : (g == 2) ? Wc : Wo;
  const float scale = (g == 2) ? 2.88539008f : 1.44269504f;  // 2*log2e : log2e
  Wint[n * 256 + k] = f16b(Ws[j * 257 + 1 + k] * scale);
  if (k == 0) {
    const float* bs = (g == 0) ? bf_ : (g == 1) ? bi_ : (g == 2) ? bc_ : bo_;
    w0b[n] = (u32)f16b(Ws[j * 257] * scale) | ((u32)f16b(bs[j] * scale) << 16);
  }
}

// Zero parity-0 pub of both sets (h_0 = 0), flags, out = bout.
__global__ void lstm_zero(uint4* __restrict__ pub4, uint4* __restrict__ flags4,
                          float* __restrict__ out, const float* __restrict__ bout) {
  int idx = blockIdx.x * 256 + threadIdx.x;
  uint4 z = uint4{0, 0, 0, 0};
  if (idx < 131072) pub4[idx] = z;                 // slot (s0,p0): 2 MB
  else if (idx < 262144) pub4[idx + 131072] = z;   // slot (s1,p0): 2 MB
  else if (idx < 264192) flags4[idx - 262144] = z; // 32 KB flags
  else { int o = idx - 264192; if (o < 8192) out[o] = bout[0]; }
}

__global__ __launch_bounds__(512, 2) void lstm_main(
    const u16* __restrict__ Wint, const u32* __restrict__ w0b,
    const float* __restrict__ x, const float* __restrict__ Wout,
    float* __restrict__ out, u16* __restrict__ pub, int* __restrict__ flags) {

  // [set][parity][0=own k-half,1=peer][32 rows x 128 cols] = 64 KB
  __shared__ __align__(16) u16 stg[2][2][2][4096];

  const int tid  = threadIdx.x;
  const int wv   = tid >> 6;
  const int lane = tid & 63;
  const int l15  = lane & 15;
  const int quad = lane >> 4;
  const int B    = blockIdx.x;
  const int mi   = (B >> 3) & 1;
  const int peer = B ^ 8;
  const int pid  = (B & 7) | ((B >> 4) << 3);   // pair 0..127
  const int rows0 = pid * 64;

  // ---- one-time: W A-fragments (128 regs, STATIC indices) ----
  f16x8 wfrag[4][8];
#pragma unroll
  for (int g = 0; g < 4; ++g)
#pragma unroll
    for (int hm = 0; hm < 2; ++hm)
#pragma unroll
      for (int ktl = 0; ktl < 4; ++ktl) {
        int kbase = (hm == 0 ? mi : 1 - mi) * 128 + ktl * 32;  // runtime, addr only
        wfrag[g][hm * 4 + ktl] = *(const f16x8*)(Wint +
            (size_t)(g * 256 + mi * 128 + wv * 16 + l15) * 256 + kbase + quad * 8);
      }
  // packed w0/bias (16 regs — funds the bb[8] transient block)
  uint4 w0bv[4];
#pragma unroll
  for (int g = 0; g < 4; ++g)
    w0bv[g] = *(const uint4*)(w0b + g * 256 + mi * 128 + wv * 16 + quad * 4);

  // zero stg (h_0 images = 0): 64 KB = 4096 uint4
#pragma unroll
  for (int i = 0; i < 8; ++i) ((uint4*)stg)[tid + i * 512] = uint4{0, 0, 0, 0};

  float cst[2][2][4];   // [set][bt][r]: cell (b = bt*16+l15, j = wv*16+quad*4+r)
#pragma unroll
  for (int s = 0; s < 2; ++s)
#pragma unroll
    for (int bt = 0; bt < 2; ++bt)
#pragma unroll
      for (int r = 0; r < 4; ++r) cst[s][bt][r] = 0.0f;

  const float* xq = x + (size_t)rows0 * 1024;
  float xcur[2][2];
#pragma unroll
  for (int s = 0; s < 2; ++s)
#pragma unroll
    for (int bt = 0; bt < 2; ++bt)
      xcur[s][bt] = xq[(size_t)(s * 32 + bt * 16 + l15) * 1024];

  int* const myflag = flags + B * 32;
  int* const pfl    = flags + peer * 32;

  __syncthreads();

// gate-major MFMA chain: acc[G][BT] += sum_sl wfrag[G][sl]*bb[sl]
#define GCHAIN(G, BT) do {                                                     \
    _Pragma("unroll")                                                          \
    for (int sl_ = 0; sl_ < 8; ++sl_)                                          \
      acc[G][BT] = __builtin_amdgcn_mfma_f32_16x16x32_f16(                     \
          wfrag[G][sl_], bb[sl_], acc[G][BT], 0, 0, 0);                        \
  } while (0)

// in-place front-end trans on a finished gate accumulator
#define FRONT(G, BT, SGN) do {                                                 \
    _Pragma("unroll")                                                          \
    for (int r_ = 0; r_ < 4; ++r_)                                             \
      acc[G][BT][r_] = fast_exp2((SGN) * acc[G][BT][r_]);                      \
  } while (0)

// load the 8 B-frags for batch-tile BT of set S, parity PAR
#define LOADBB(S, PAR, BT) do {                                                \
    int b_ = (BT) * 16 + l15;                                                  \
    _Pragma("unroll")                                                          \
    for (int sl_ = 0; sl_ < 8; ++sl_) {                                        \
      int cp_ = ((sl_ & 3) * 4 + quad) ^ (b_ & 15);                            \
      bb[sl_] = *(const f16x8*)(&stg[S][PAR][sl_ >> 2][0] + b_ * 128 + cp_ * 8); \
    }                                                                          \
  } while (0)

// combine + publish for batch-tile BT of set S (acc holds Ef,Ei,C,og):
// c' = (c*Y+(C-1)*X)*rcp(X*Y); h = (T-1)*rcp((1+Eo)(T+1)), T bounded by clamp.
#define COMBINE_PUB(S, BT) do {                                                \
    int b_ = (BT) * 16 + l15;                                                  \
    float h0_, h1_, h2_, h3_;                                                  \
    _Pragma("unroll")                                                          \
    for (int r_ = 0; r_ < 4; ++r_) {                                           \
      float Ef_ = acc[0][BT][r_], Ei_ = acc[1][BT][r_];                        \
      float C_  = acc[2][BT][r_];                                              \
      float Eo_ = fast_exp2(-acc[3][BT][r_]);                                  \
      float X_  = 1.0f + Ef_;                                                  \
      float Y_  = (1.0f + Ei_) * (C_ + 1.0f);                                  \
      float num_ = cst[S][BT][r_] * Y_ + (C_ - 1.0f) * X_;                     \
      float c2_  = num_ * fast_rcp(X_ * Y_);                                   \
      cst[S][BT][r_] = c2_;                                                    \
      float cc_ = fminf(fmaxf(c2_, -40.0f), 40.0f);                            \
      float T_  = fast_exp2(2.88539008f * cc_);                                \
      float hv_ = (T_ - 1.0f) * fast_rcp((1.0f + Eo_) * (T_ + 1.0f));          \
      if (r_ == 0) h0_ = hv_; else if (r_ == 1) h1_ = hv_;                     \
      else if (r_ == 2) h2_ = hv_; else h3_ = hv_;                             \
    }                                                                          \
    u32 lo_ = (u32)f16b(h0_) | ((u32)f16b(h1_) << 16);                         \
    u32 hi_ = (u32)f16b(h2_) | ((u32)f16b(h3_) << 16);                         \
    int c16_ = wv * 2 + (quad >> 1);                                           \
    int off_ = b_ * 128 + (c16_ ^ (b_ & 15)) * 8 + (quad & 1) * 4;             \
    *(uint2*)(lb + off_) = uint2{lo_, hi_};                                    \
    *(uint2*)(pb + off_) = uint2{lo_, hi_};                                    \
  } while (0)

#pragma unroll 1
  for (int t = 0; t < 1024; ++t) {
#pragma unroll
    for (int s = 0; s < 2; ++s) {
      // 1. acc init = x*w0 + bias (packed fp16 pairs, inline unpack)
      f32x4 acc[4][2];
#pragma unroll
      for (int g = 0; g < 4; ++g) {
        u32 pka[4] = {w0bv[g].x, w0bv[g].y, w0bv[g].z, w0bv[g].w};
#pragma unroll
        for (int r = 0; r < 4; ++r) {
          float w0f = h2f((u16)pka[r]), bsf = h2f((u16)(pka[r] >> 16));
          acc[g][0][r] = xcur[s][0] * w0f + bsf;
          acc[g][1][r] = xcur[s][1] * w0f + bsf;
        }
      }
      // x prefetch for (s, t+1) — drained by phase-end barrier
#pragma unroll
      for (int bt = 0; bt < 2; ++bt)
        xcur[s][bt] = xq[(size_t)(s * 32 + bt * 16 + l15) * 1024 + ((t + 1) & 1023)];

      u16* pb = pub_base(pub, s, (t + 1) & 1, pid, mi);
      u16* lb = &stg[s][(t + 1) & 1][0][0];
      f16x8 bb[8];

      // 2. bt0: gate-major chains with in-place front-end trans between gates
      LOADBB(s, t & 1, 0);
      GCHAIN(0, 0);
      GCHAIN(1, 0); FRONT(0, 0, -1.0f);   // Ef0 weaves with gateI chain
      GCHAIN(2, 0); FRONT(1, 0, -1.0f);   // Ei0 || gateC
      GCHAIN(3, 0); FRONT(2, 0,  1.0f);   // C0  || gateO
      // 3. combine0 + publish0 — weaves with bt1's chains below
      COMBINE_PUB(s, 0);

      // 4. bt1: same structure (bb regs reused)
      LOADBB(s, t & 1, 1);
      GCHAIN(0, 1);
      GCHAIN(1, 1); FRONT(0, 1, -1.0f);
      GCHAIN(2, 1); FRONT(1, 1, -1.0f);
      GCHAIN(3, 1); FRONT(2, 1,  1.0f);

      // 5. poll at point-of-need + slice DMA of PEER half for set s^1's next
      //    consumption (r15 verbatim — the only transport that measures fresh)
      const int tn = (s == 0) ? t : t + 1;
      if (tn < 1024) {
        while (__hip_atomic_load(pfl + (s ^ 1) * 16, __ATOMIC_RELAXED,
                                 __HIP_MEMORY_SCOPE_AGENT) < tn)
          __builtin_amdgcn_s_sleep(1);
        const u16* srcP = pub_base(pub, s ^ 1, tn & 1, pid, 1 - mi);
        __builtin_amdgcn_global_load_lds(
            (const __attribute__((address_space(1))) u32*)(srcP + wv * 512 + lane * 8),
            (__attribute__((address_space(3))) u32*)(&stg[s ^ 1][tn & 1][1][wv * 512]),
            16, 0, 0);
      }

      // 6. combine1 + publish1 — covers the DMA latency before the barrier
      COMBINE_PUB(s, 1);

      // 7. single barrier (drains publish + DMA + x loads + ds_writes) + flag
      __syncthreads();
      if (tid == 0)
        __hip_atomic_store(myflag + s * 16, t + 1, __ATOMIC_RELAXED,
                           __HIP_MEMORY_SCOPE_AGENT);
    }
  }

  // ---- out[b] += (own j-half of h_1024) . Wout  (out pre-set to bout) ----
  if (tid < 64) {
    int s = tid >> 5, b = tid & 31;
    const u16* pbase = pub_base(pub, s, 0, pid, mi);  // parity of t=1024 is 0
    float a = 0.0f;
#pragma unroll
    for (int c = 0; c < 16; ++c) {
      f16x8 hv = *(const f16x8*)(pbase + b * 128 + ((c ^ (b & 15)) * 8));
#pragma unroll
      for (int e = 0; e < 8; ++e) a += (float)hv[e] * Wout[mi * 128 + c * 8 + e];
    }
    atomicAdd(&out[rows0 + s * 32 + b], a);
  }
#undef GCHAIN
#undef FRONT
#undef LOADBB
#undef COMBINE_PUB
}

extern "C" void kernel_launch(void* const* d_in, const int* in_sizes, int n_in,
                              void* d_out, int out_size, void* d_ws, size_t ws_size,
                              hipStream_t stream) {
  const float* x    = (const float*)d_in[0];
  const float* Wf   = (const float*)d_in[1];
  const float* bf_  = (const float*)d_in[2];
  const float* Wi   = (const float*)d_in[3];
  const float* bi_  = (const float*)d_in[4];
  const float* Wc   = (const float*)d_in[5];
  const float* bc_  = (const float*)d_in[6];
  const float* Wo   = (const float*)d_in[7];
  const float* bo_  = (const float*)d_in[8];
  const float* Wout = (const float*)d_in[9];
  const float* bout = (const float*)d_in[10];

  u16* Wint  = (u16*)((char*)d_ws + WINT_OFF);
  u32* w0b   = (u32*)((char*)d_ws + W0B_OFF);
  int* flags = (int*)((char*)d_ws + FLAG_OFF);
  u16* pub   = (u16*)((char*)d_ws + PUB_OFF);

  lstm_prep<<<1024, 256, 0, stream>>>(Wf, Wi, Wc, Wo, bf_, bi_, bc_, bo_, Wint, w0b);
  lstm_zero<<<1064, 256, 0, stream>>>((uint4*)pub, (uint4*)flags, (float*)d_out, bout);
  lstm_main<<<256, 512, 0, stream>>>(Wint, w0b, x, Wout, (float*)d_out, pub, flags);
}